// Round 1
// baseline (2451.797 us; speedup 1.0000x reference)
//
#include <hip/hip_runtime.h>
#include <hip/hip_bf16.h>

#define N_NODES 100000
#define N_EDGES 1600000
#define F_IN 770
#define HID 64
#define NREL 3

// ---------------------------------------------------------------- CSR build
__global__ void k_deg(const int* __restrict__ dstv, int* __restrict__ deg, int E) {
    int e = blockIdx.x * blockDim.x + threadIdx.x;
    if (e < E) atomicAdd(&deg[dstv[e]], 1);
}

// block-local exclusive scan (chunk = 256), writes block totals to csums
__global__ void k_scan1(const int* __restrict__ deg, int* __restrict__ excl,
                        int* __restrict__ csums, int n) {
    __shared__ int a[256], b[256];
    int tid = threadIdx.x;
    int g = blockIdx.x * 256 + tid;
    int v = (g < n) ? deg[g] : 0;
    int *cur = a, *nxt = b;
    cur[tid] = v;
    __syncthreads();
    for (int off = 1; off < 256; off <<= 1) {
        int t = cur[tid];
        if (tid >= off) t += cur[tid - off];
        nxt[tid] = t;
        __syncthreads();
        int* tmp = cur; cur = nxt; nxt = tmp;
    }
    int inc = cur[tid];
    if (g < n) excl[g] = inc - v;            // block-local exclusive
    if (tid == 255) csums[blockIdx.x] = inc; // block total
}

// single block: exclusive scan of up to 512 chunk sums, in place
__global__ void k_scan2(int* __restrict__ csums, int nchunks) {
    __shared__ int a[512], b[512];
    int tid = threadIdx.x;
    int v = (tid < nchunks) ? csums[tid] : 0;
    int *cur = a, *nxt = b;
    cur[tid] = v;
    __syncthreads();
    for (int off = 1; off < 512; off <<= 1) {
        int t = cur[tid];
        if (tid >= off) t += cur[tid - off];
        nxt[tid] = t;
        __syncthreads();
        int* tmp = cur; cur = nxt; nxt = tmp;
    }
    int inc = cur[tid];
    if (tid < nchunks) csums[tid] = inc - v;  // exclusive
}

__global__ void k_scan3(int* __restrict__ row_ptr, const int* __restrict__ csums,
                        int* __restrict__ cursor, int n, int E) {
    int g = blockIdx.x * blockDim.x + threadIdx.x;
    if (g < n) {
        int v = row_ptr[g] + csums[g >> 8];
        row_ptr[g] = v;
        cursor[g] = v;
    }
    if (g == n) row_ptr[n] = E;
}

// scatter edges into CSR slots; pack src (17 bits) | rel (bits 17..18)
__global__ void k_fill(const int* __restrict__ srcv, const int* __restrict__ dstv,
                       const int* __restrict__ et, int* __restrict__ cursor,
                       int* __restrict__ esrt, int E) {
    int e = blockIdx.x * blockDim.x + threadIdx.x;
    if (e < E) {
        int d = dstv[e];
        int pos = atomicAdd(&cursor[d], 1);
        esrt[pos] = srcv[e] | (et[e] << 17);
    }
}

// ---------------------------------------------------------------- weight packing
// Wcat[k][j], j<64 -> root[k][j]; else r=(j>>6)-1, jj=j&63 -> W[r][k][jj]
__global__ void k_pack(const float* __restrict__ root, const float* __restrict__ W,
                       float* __restrict__ out, int K) {
    int idx = blockIdx.x * blockDim.x + threadIdx.x;
    if (idx >= K * 256) return;
    int k = idx >> 8, j = idx & 255;
    float v;
    if (j < 64) v = root[k * 64 + j];
    else {
        int r = (j >> 6) - 1, jj = j & 63;
        v = W[(r * K + k) * 64 + jj];
    }
    out[idx] = v;
}

// Wab[k][j] (64x128): j<64 -> ew1[k][j]; else -> ew1[64+k][j-64]
__global__ void k_packwab(const float* __restrict__ ew1, float* __restrict__ out) {
    int idx = blockIdx.x * blockDim.x + threadIdx.x;
    if (idx >= 64 * 128) return;
    int k = idx >> 7, j = idx & 127;
    out[idx] = (j < 64) ? ew1[k * 64 + j] : ew1[(64 + k) * 64 + (j - 64)];
}

// ---------------------------------------------------------------- fp32 tiled GEMM
// C[M,Nc] = A[M,K] @ B[K,Nc]; BM=BN=64, BK=16; 256 threads, 4x4 per thread.
__global__ __launch_bounds__(256) void k_gemm(const float* __restrict__ A,
                                              const float* __restrict__ B,
                                              float* __restrict__ C,
                                              int M, int K, int Nc) {
    __shared__ float As[16][68];   // padded, rows 16B-aligned (68*4=272=17*16)
    __shared__ float Bs[16][64];
    int tid = threadIdx.x;
    int m0 = blockIdx.x * 64;
    int n0 = blockIdx.y * 64;
    int tx = tid & 15;   // n dir
    int ty = tid >> 4;   // m dir
    int lka = tid & 15;  // A-load k
    int lma = tid >> 4;  // A-load m base
    int lnb = tid & 63;  // B-load n
    int lkb = tid >> 6;  // B-load k base
    float c[4][4] = {};
    int ktiles = (K + 15) >> 4;
    for (int kt = 0; kt < ktiles; ++kt) {
        int k0 = kt << 4;
        #pragma unroll
        for (int p = 0; p < 4; ++p) {
            int mm = lma + 16 * p;
            int gm = m0 + mm, gk = k0 + lka;
            As[lka][mm] = (gm < M && gk < K) ? A[gm * K + gk] : 0.f;
        }
        #pragma unroll
        for (int p = 0; p < 4; ++p) {
            int kk = lkb + 4 * p;
            int gk = k0 + kk;
            Bs[kk][lnb] = (gk < K) ? B[gk * Nc + n0 + lnb] : 0.f;
        }
        __syncthreads();
        #pragma unroll
        for (int kk = 0; kk < 16; ++kk) {
            float a[4], b[4];
            *(float4*)a = *(const float4*)&As[kk][ty * 4];
            *(float4*)b = *(const float4*)&Bs[kk][tx * 4];
            #pragma unroll
            for (int i = 0; i < 4; ++i)
                #pragma unroll
                for (int j = 0; j < 4; ++j)
                    c[i][j] += a[i] * b[j];
        }
        __syncthreads();
    }
    #pragma unroll
    for (int i = 0; i < 4; ++i) {
        int gm = m0 + ty * 4 + i;
        if (gm < M) {
            float4 v = make_float4(c[i][0], c[i][1], c[i][2], c[i][3]);
            *(float4*)&C[gm * Nc + n0 + tx * 4] = v;
        }
    }
}

// ---------------------------------------------------------------- RGCN aggregation
// One wave per node; lane = feature. Y: [N,256] (cols 0..63 self, 64+64r.. msgs)
__global__ __launch_bounds__(256) void k_agg(const float* __restrict__ Y,
                                             const int* __restrict__ row_ptr,
                                             const int* __restrict__ esrt,
                                             const float* __restrict__ bias,
                                             const float* __restrict__ resid,
                                             float* __restrict__ Xout,
                                             int do_relu, int n) {
    int wid = (blockIdx.x * blockDim.x + threadIdx.x) >> 6;
    int lane = threadIdx.x & 63;
    if (wid >= n) return;
    int beg = row_ptr[wid], end = row_ptr[wid + 1];
    float a0 = 0.f, a1 = 0.f, a2 = 0.f;
    int c0 = 0, c1 = 0, c2 = 0;
    for (int e = beg; e < end; ++e) {
        int p = esrt[e];
        int s = p & 0x1FFFF;
        int r = p >> 17;
        float v = Y[s * 256 + 64 + (r << 6) + lane];
        if (r == 0) { a0 += v; c0++; }
        else if (r == 1) { a1 += v; c1++; }
        else { a2 += v; c2++; }
    }
    float res = Y[wid * 256 + lane] + bias[lane];
    if (c0) res += a0 / (float)c0;
    if (c1) res += a1 / (float)c1;
    if (c2) res += a2 / (float)c2;
    if (do_relu) res = fmaxf(res, 0.f);
    if (resid) res += resid[wid * 64 + lane];
    Xout[wid * 64 + lane] = res;
}

// ---------------------------------------------------------------- node head
__global__ __launch_bounds__(256) void k_nodehead(const float* __restrict__ X3,
                                                  const float* __restrict__ nw1,
                                                  const float* __restrict__ nb1,
                                                  const float* __restrict__ nw2,
                                                  const float* __restrict__ nb2,
                                                  float* __restrict__ out, int n) {
    __shared__ float w1[64 * 32];
    __shared__ float w2[32 * 2];
    __shared__ float b1s[32];
    __shared__ float b2s[2];
    int tid = threadIdx.x;
    for (int i = tid; i < 64 * 32; i += 256) w1[i] = nw1[i];
    for (int i = tid; i < 32 * 2; i += 256) w2[i] = nw2[i];
    if (tid < 32) b1s[tid] = nb1[tid];
    if (tid < 2) b2s[tid] = nb2[tid];
    __syncthreads();
    int g = blockIdx.x * blockDim.x + tid;
    if (g >= n) return;
    float x[64];
    #pragma unroll
    for (int q = 0; q < 16; ++q)
        *(float4*)&x[q * 4] = *(const float4*)&X3[g * 64 + q * 4];
    float o0 = b2s[0], o1 = b2s[1];
    for (int j = 0; j < 32; ++j) {
        float h = b1s[j];
        #pragma unroll
        for (int k = 0; k < 64; ++k) h += x[k] * w1[k * 32 + j];
        h = fmaxf(h, 0.f);
        o0 += h * w2[j * 2 + 0];
        o1 += h * w2[j * 2 + 1];
    }
    out[g * 2 + 0] = o0;
    out[g * 2 + 1] = o1;
}

// ---------------------------------------------------------------- edge head
// AB: [N,128] -- A = x3@ew1[:64]  (cols 0..63), B = x3@ew1[64:] (cols 64..127)
__global__ __launch_bounds__(256) void k_edgehead(const float* __restrict__ AB,
                                                  const int* __restrict__ srcv,
                                                  const int* __restrict__ dstv,
                                                  const float* __restrict__ eb1,
                                                  const float* __restrict__ ew2,
                                                  const float* __restrict__ eb2,
                                                  const float* __restrict__ ew3,
                                                  const float* __restrict__ eb3,
                                                  float* __restrict__ out, int E) {
    __shared__ float w2[64 * 32];
    __shared__ float w3[32 * 3];
    __shared__ float b1s[64];
    __shared__ float b2s[32];
    __shared__ float b3s[3];
    int tid = threadIdx.x;
    for (int i = tid; i < 64 * 32; i += 256) w2[i] = ew2[i];
    for (int i = tid; i < 32 * 3; i += 256) w3[i] = ew3[i];
    if (tid < 64) b1s[tid] = eb1[tid];
    if (tid < 32) b2s[tid] = eb2[tid];
    if (tid < 3) b3s[tid] = eb3[tid];
    __syncthreads();
    int e = blockIdx.x * blockDim.x + tid;
    if (e >= E) return;
    int s = srcv[e], d = dstv[e];
    const float4* Ar = (const float4*)(AB + (size_t)s * 128);
    const float4* Br = (const float4*)(AB + (size_t)d * 128 + 64);
    float h2[32];
    #pragma unroll
    for (int j = 0; j < 32; ++j) h2[j] = 0.f;
    #pragma unroll 4
    for (int q = 0; q < 16; ++q) {
        float av[4], bv[4];
        *(float4*)av = Ar[q];
        *(float4*)bv = Br[q];
        #pragma unroll
        for (int t = 0; t < 4; ++t) {
            int k = q * 4 + t;
            float h1 = fmaxf(av[t] + bv[t] + b1s[k], 0.f);
            #pragma unroll
            for (int j = 0; j < 32; ++j) h2[j] += h1 * w2[k * 32 + j];
        }
    }
    float o0 = b3s[0], o1 = b3s[1], o2 = b3s[2];
    #pragma unroll
    for (int j = 0; j < 32; ++j) {
        float hh = fmaxf(h2[j] + b2s[j], 0.f);
        o0 += hh * w3[j * 3 + 0];
        o1 += hh * w3[j * 3 + 1];
        o2 += hh * w3[j * 3 + 2];
    }
    out[200000 + (size_t)e * 3 + 0] = o0;
    out[200000 + (size_t)e * 3 + 1] = o1;
    out[200000 + (size_t)e * 3 + 2] = o2;
}

// ---------------------------------------------------------------- launch
extern "C" void kernel_launch(void* const* d_in, const int* in_sizes, int n_in,
                              void* d_out, int out_size, void* d_ws, size_t ws_size,
                              hipStream_t stream) {
    const float* x     = (const float*)d_in[0];
    const int*   ei    = (const int*)d_in[1];
    const int*   et    = (const int*)d_in[2];
    const float* W1    = (const float*)d_in[3];
    const float* root1 = (const float*)d_in[4];
    const float* b1    = (const float*)d_in[5];
    const float* W2    = (const float*)d_in[6];
    const float* root2 = (const float*)d_in[7];
    const float* b2    = (const float*)d_in[8];
    const float* W3    = (const float*)d_in[9];
    const float* root3 = (const float*)d_in[10];
    const float* b3    = (const float*)d_in[11];
    const float* nw1   = (const float*)d_in[12];
    const float* nb1   = (const float*)d_in[13];
    const float* nw2   = (const float*)d_in[14];
    const float* nb2   = (const float*)d_in[15];
    const float* ew1   = (const float*)d_in[16];
    const float* eb1   = (const float*)d_in[17];
    const float* ew2   = (const float*)d_in[18];
    const float* eb2   = (const float*)d_in[19];
    const float* ew3   = (const float*)d_in[20];
    const float* eb3   = (const float*)d_in[21];
    float* out = (float*)d_out;

    const int N = N_NODES, E = N_EDGES;
    const int* srcv = ei;
    const int* dstv = ei + E;

    // workspace layout (floats then ints)
    float* fp = (float*)d_ws;
    float* Y    = fp;  fp += (size_t)N * 256;   // also reused for AB [N,128]
    float* X1   = fp;  fp += (size_t)N * 64;
    float* X2   = fp;  fp += (size_t)N * 64;
    float* X3   = fp;  fp += (size_t)N * 64;
    float* Wcat = fp;  fp += (size_t)F_IN * 256;
    float* Wab  = fp;  fp += 64 * 128;
    int* ip = (int*)fp;
    int* deg     = ip;  ip += N;
    int* row_ptr = ip;  ip += N + 1;
    int* cursor  = ip;  ip += N;
    int* esrt    = ip;  ip += E;
    int* csums   = ip;  ip += 512;

    // ---- CSR build (once per call; reused by all 3 layers)
    hipMemsetAsync(deg, 0, N * sizeof(int), stream);
    k_deg<<<(E + 255) / 256, 256, 0, stream>>>(dstv, deg, E);
    int nchunks = (N + 255) / 256;  // 391
    k_scan1<<<nchunks, 256, 0, stream>>>(deg, row_ptr, csums, N);
    k_scan2<<<1, 512, 0, stream>>>(csums, nchunks);
    k_scan3<<<(N + 256) / 256, 256, 0, stream>>>(row_ptr, csums, cursor, N, E);
    k_fill<<<(E + 255) / 256, 256, 0, stream>>>(srcv, dstv, et, cursor, esrt, E);

    dim3 gemm_grid_big((N + 63) / 64, 4);

    // ---- layer 1
    k_pack<<<(F_IN * 256 + 255) / 256, 256, 0, stream>>>(root1, W1, Wcat, F_IN);
    k_gemm<<<gemm_grid_big, 256, 0, stream>>>(x, Wcat, Y, N, F_IN, 256);
    k_agg<<<(N * 64 + 255) / 256, 256, 0, stream>>>(Y, row_ptr, esrt, b1, nullptr, X1, 1, N);

    // ---- layer 2
    k_pack<<<(64 * 256 + 255) / 256, 256, 0, stream>>>(root2, W2, Wcat, 64);
    k_gemm<<<gemm_grid_big, 256, 0, stream>>>(X1, Wcat, Y, N, 64, 256);
    k_agg<<<(N * 64 + 255) / 256, 256, 0, stream>>>(Y, row_ptr, esrt, b2, nullptr, X2, 1, N);

    // ---- layer 3 (+ residual x1, no relu)
    k_pack<<<(64 * 256 + 255) / 256, 256, 0, stream>>>(root3, W3, Wcat, 64);
    k_gemm<<<gemm_grid_big, 256, 0, stream>>>(X2, Wcat, Y, N, 64, 256);
    k_agg<<<(N * 64 + 255) / 256, 256, 0, stream>>>(Y, row_ptr, esrt, b3, X1, X3, 0, N);

    // ---- node head -> out[0 .. 2N)
    k_nodehead<<<(N + 255) / 256, 256, 0, stream>>>(X3, nw1, nb1, nw2, nb2, out, N);

    // ---- edge head: precompute AB = [x3@ew1[:64] | x3@ew1[64:]] into Y
    k_packwab<<<(64 * 128 + 255) / 256, 256, 0, stream>>>(ew1, Wab);
    dim3 gemm_grid_ab((N + 63) / 64, 2);
    k_gemm<<<gemm_grid_ab, 256, 0, stream>>>(X3, Wab, Y, N, 64, 128);
    k_edgehead<<<(E + 255) / 256, 256, 0, stream>>>(Y, srcv, dstv, eb1, ew2, eb2, ew3, eb3, out, E);
}

// Round 4
// 1621.718 us; speedup vs baseline: 1.5119x; 1.5119x over previous
//
#include <hip/hip_runtime.h>

typedef unsigned int uint;
typedef unsigned short ushort;
typedef short short8 __attribute__((ext_vector_type(8)));
typedef float f32x4 __attribute__((ext_vector_type(4)));
typedef float float4u __attribute__((ext_vector_type(4), aligned(4)));

#define MN 100000
#define ME 1600000
#define KIN 770

__device__ __forceinline__ ushort f2bf(float f) {
    union { float f; uint u; } c; c.f = f;
    uint r = (c.u + 0x7fffu + ((c.u >> 16) & 1u)) >> 16;
    return (ushort)r;
}
__device__ __forceinline__ float bf2f(ushort h) {
    union { uint u; float f; } c; c.u = ((uint)h) << 16;
    return c.f;
}
__device__ __forceinline__ float bflo(uint w) {
    union { uint u; float f; } c; c.u = w << 16; return c.f;
}
__device__ __forceinline__ float bfhi(uint w) {
    union { uint u; float f; } c; c.u = w & 0xffff0000u; return c.f;
}

// ---------------------------------------------------------------- CSR build
__global__ void k_deg(const int* __restrict__ dstv, int* __restrict__ deg, int E) {
    int e = blockIdx.x * blockDim.x + threadIdx.x;
    if (e < E) atomicAdd(&deg[dstv[e]], 1);
}

__global__ void k_scan1(const int* __restrict__ deg, int* __restrict__ excl,
                        int* __restrict__ csums, int n) {
    __shared__ int a[256], b[256];
    int tid = threadIdx.x;
    int g = blockIdx.x * 256 + tid;
    int v = (g < n) ? deg[g] : 0;
    int *cur = a, *nxt = b;
    cur[tid] = v;
    __syncthreads();
    for (int off = 1; off < 256; off <<= 1) {
        int t = cur[tid];
        if (tid >= off) t += cur[tid - off];
        nxt[tid] = t;
        __syncthreads();
        int* tmp = cur; cur = nxt; nxt = tmp;
    }
    int inc = cur[tid];
    if (g < n) excl[g] = inc - v;
    if (tid == 255) csums[blockIdx.x] = inc;
}

__global__ void k_scan2(int* __restrict__ csums, int nchunks) {
    __shared__ int a[512], b[512];
    int tid = threadIdx.x;
    int v = (tid < nchunks) ? csums[tid] : 0;
    int *cur = a, *nxt = b;
    cur[tid] = v;
    __syncthreads();
    for (int off = 1; off < 512; off <<= 1) {
        int t = cur[tid];
        if (tid >= off) t += cur[tid - off];
        nxt[tid] = t;
        __syncthreads();
        int* tmp = cur; cur = nxt; nxt = tmp;
    }
    int inc = cur[tid];
    if (tid < nchunks) csums[tid] = inc - v;
}

__global__ void k_scan3(int* __restrict__ row_ptr, const int* __restrict__ csums,
                        int* __restrict__ cursor, int n, int E) {
    int g = blockIdx.x * blockDim.x + threadIdx.x;
    if (g < n) {
        int v = row_ptr[g] + csums[g >> 8];
        row_ptr[g] = v;
        cursor[g] = v;
    }
    if (g == n) row_ptr[n] = E;
}

__global__ void k_fill(const int* __restrict__ srcv, const int* __restrict__ dstv,
                       const int* __restrict__ et, int* __restrict__ cursor,
                       int* __restrict__ esrt, int E) {
    int e = blockIdx.x * blockDim.x + threadIdx.x;
    if (e < E) {
        int d = dstv[e];
        int pos = atomicAdd(&cursor[d], 1);
        esrt[pos] = srcv[e] | (et[e] << 17);
    }
}

// ---------------------------------------------------------------- weight packing (B^T bf16)
// out[j][k] (stride Kp): j<64 -> root[k][j]; else r=(j>>6)-1 -> W[r][k][j&63]; zero-pad k>=K
__global__ void k_pack_bt(const float* __restrict__ root, const float* __restrict__ W,
                          ushort* __restrict__ out, int K, int Kp) {
    int idx = blockIdx.x * blockDim.x + threadIdx.x;
    if (idx >= 256 * Kp) return;
    int j = idx / Kp, k = idx - j * Kp;
    float v = 0.f;
    if (k < K) {
        if (j < 64) v = root[k * 64 + j];
        else {
            int r = (j >> 6) - 1, jj = j & 63;
            v = W[((size_t)r * K + k) * 64 + jj];
        }
    }
    out[idx] = f2bf(v);
}

// BTab[j][k] (128 x 64): j<64 -> ew1[k][j]; else -> ew1[64+k][j-64]
__global__ void k_packwab_bt(const float* __restrict__ ew1, ushort* __restrict__ out) {
    int idx = blockIdx.x * blockDim.x + threadIdx.x;
    if (idx >= 128 * 64) return;
    int j = idx >> 6, k = idx & 63;
    float v = (j < 64) ? ew1[k * 64 + j] : ew1[(64 + k) * 64 + (j - 64)];
    out[idx] = f2bf(v);
}

// ---------------------------------------------------------------- bf16 MFMA GEMM
// C[M,Nc](bf16) = A[M,K] @ BT[Nc,Kp]^T.  BM=128, BN=128/256, BK=32, 512 thr (8 waves 2x4).
// AFP32: A is fp32 (converted during staging, ragged K ok); else bf16 (K%32==0).
template<bool AFP32, int BN>
__global__ __launch_bounds__(512) void k_mm(const void* __restrict__ Ain,
                                            const ushort* __restrict__ BT,
                                            ushort* __restrict__ C,
                                            int M, int K, int Kp, int Nc) {
    constexpr int WN = BN / 4;            // wave tile N
    constexpr int NF = WN / 16;           // 16x16 frags per wave in N
    constexpr int NBS = (4 * BN) / 512;   // B staging stores per thread
    __shared__ uint4 lds4[512 + 4 * BN];  // As: 512 slots (kq*128+row), Bs: 4*BN (kq*BN+col)
    int tid = threadIdx.x;
    int lane = tid & 63, wid = tid >> 6;
    int l15 = lane & 15, kq = lane >> 4;
    int wm = wid >> 2, wn = wid & 3;
    int m0 = blockIdx.x * 128;
    int n0 = blockIdx.y * BN;

    int s_kp = tid >> 7;       // 0..3
    int s_row = tid & 127;
    int gm = m0 + s_row; if (gm > M - 1) gm = M - 1;

    const float*  Af = (const float*)Ain;
    const ushort* Ab = (const ushort*)Ain;

    f32x4 acc[4][NF];
    #pragma unroll
    for (int m = 0; m < 4; ++m)
        #pragma unroll
        for (int n = 0; n < NF; ++n)
            acc[m][n] = (f32x4)0.f;

    int nkt = (K + 31) >> 5;
    uint4 stA, stB[NBS];

    auto loadA = [&](int kt) {
        int k0 = kt << 5;
        int kb = k0 + s_kp * 8;
        if constexpr (AFP32) {
            const float* ap = Af + (size_t)gm * K + kb;
            float v[8];
            if (k0 + 32 <= K) {
                *(float4u*)&v[0] = *(const float4u*)ap;
                *(float4u*)&v[4] = *(const float4u*)(ap + 4);
            } else {
                #pragma unroll
                for (int i = 0; i < 8; ++i)
                    v[i] = (kb + i < K) ? ap[i] : 0.f;
            }
            uint w[4];
            #pragma unroll
            for (int i = 0; i < 4; ++i)
                w[i] = (uint)f2bf(v[2 * i]) | ((uint)f2bf(v[2 * i + 1]) << 16);
            stA = make_uint4(w[0], w[1], w[2], w[3]);
        } else {
            stA = *(const uint4*)(Ab + (size_t)gm * K + kb);
        }
    };
    auto loadB = [&](int kt) {
        int k0 = kt << 5;
        #pragma unroll
        for (int is = 0; is < NBS; ++is) {
            int slot = is * 512 + tid;
            int kp = slot / BN;
            int col = slot & (BN - 1);
            stB[is] = *(const uint4*)(BT + (size_t)(n0 + col) * Kp + k0 + kp * 8);
        }
    };

    loadA(0); loadB(0);
    for (int kt = 0; kt < nkt; ++kt) {
        __syncthreads();
        lds4[tid] = stA;
        #pragma unroll
        for (int is = 0; is < NBS; ++is)
            lds4[512 + is * 512 + tid] = stB[is];
        __syncthreads();
        if (kt + 1 < nkt) { loadA(kt + 1); loadB(kt + 1); }
        const short8* Asv = (const short8*)lds4;
        const short8* Bsv = (const short8*)(lds4 + 512);
        short8 a[4], b[NF];
        #pragma unroll
        for (int m = 0; m < 4; ++m)
            a[m] = Asv[kq * 128 + wm * 64 + m * 16 + l15];
        #pragma unroll
        for (int n = 0; n < NF; ++n)
            b[n] = Bsv[kq * BN + wn * WN + n * 16 + l15];
        #pragma unroll
        for (int m = 0; m < 4; ++m)
            #pragma unroll
            for (int n = 0; n < NF; ++n)
                acc[m][n] = __builtin_amdgcn_mfma_f32_16x16x32_bf16(a[m], b[n], acc[m][n], 0, 0, 0);
    }

    #pragma unroll
    for (int m = 0; m < 4; ++m) {
        int rbase = m0 + wm * 64 + m * 16 + kq * 4;
        #pragma unroll
        for (int n = 0; n < NF; ++n) {
            int col = n0 + wn * WN + n * 16 + l15;
            #pragma unroll
            for (int rg = 0; rg < 4; ++rg) {
                int r = rbase + rg;
                if (r < M) C[(size_t)r * Nc + col] = f2bf(acc[m][n][rg]);
            }
        }
    }
}

// ---------------------------------------------------------------- RGCN aggregation (bf16)
__global__ __launch_bounds__(256) void k_agg(const ushort* __restrict__ Y,
                                             const int* __restrict__ row_ptr,
                                             const int* __restrict__ esrt,
                                             const float* __restrict__ bias,
                                             const ushort* __restrict__ resid,
                                             ushort* __restrict__ Xout,
                                             int do_relu, int n) {
    int wid = (blockIdx.x * blockDim.x + threadIdx.x) >> 6;
    int lane = threadIdx.x & 63;
    if (wid >= n) return;
    int beg = row_ptr[wid], end = row_ptr[wid + 1];
    float a0 = 0.f, a1 = 0.f, a2 = 0.f;
    int c0 = 0, c1 = 0, c2 = 0;
    for (int e = beg; e < end; ++e) {
        int p = esrt[e];
        int s = p & 0x1FFFF;
        int r = p >> 17;
        float v = bf2f(Y[(size_t)s * 256 + 64 + (r << 6) + lane]);
        if (r == 0) { a0 += v; c0++; }
        else if (r == 1) { a1 += v; c1++; }
        else { a2 += v; c2++; }
    }
    float res = bf2f(Y[(size_t)wid * 256 + lane]) + bias[lane];
    if (c0) res += a0 / (float)c0;
    if (c1) res += a1 / (float)c1;
    if (c2) res += a2 / (float)c2;
    if (do_relu) res = fmaxf(res, 0.f);
    if (resid) res += bf2f(resid[(size_t)wid * 64 + lane]);
    Xout[(size_t)wid * 64 + lane] = f2bf(res);
}

// ---------------------------------------------------------------- node head
__global__ __launch_bounds__(256) void k_nodehead(const ushort* __restrict__ X3,
                                                  const float* __restrict__ nw1,
                                                  const float* __restrict__ nb1,
                                                  const float* __restrict__ nw2,
                                                  const float* __restrict__ nb2,
                                                  float* __restrict__ out, int n) {
    __shared__ float w1[64 * 32];
    __shared__ float w2[32 * 2];
    __shared__ float b1s[32];
    __shared__ float b2s[2];
    int tid = threadIdx.x;
    for (int i = tid; i < 64 * 32; i += 256) w1[i] = nw1[i];
    for (int i = tid; i < 32 * 2; i += 256) w2[i] = nw2[i];
    if (tid < 32) b1s[tid] = nb1[tid];
    if (tid < 2) b2s[tid] = nb2[tid];
    __syncthreads();
    int g = blockIdx.x * blockDim.x + tid;
    if (g >= n) return;
    float x[64];
    const uint4* xr = (const uint4*)(X3 + (size_t)g * 64);
    #pragma unroll
    for (int q = 0; q < 8; ++q) {
        uint4 u = xr[q];
        x[q * 8 + 0] = bflo(u.x); x[q * 8 + 1] = bfhi(u.x);
        x[q * 8 + 2] = bflo(u.y); x[q * 8 + 3] = bfhi(u.y);
        x[q * 8 + 4] = bflo(u.z); x[q * 8 + 5] = bfhi(u.z);
        x[q * 8 + 6] = bflo(u.w); x[q * 8 + 7] = bfhi(u.w);
    }
    float o0 = b2s[0], o1 = b2s[1];
    for (int j = 0; j < 32; ++j) {
        float h = b1s[j];
        #pragma unroll
        for (int k = 0; k < 64; ++k) h += x[k] * w1[k * 32 + j];
        h = fmaxf(h, 0.f);
        o0 += h * w2[j * 2 + 0];
        o1 += h * w2[j * 2 + 1];
    }
    out[g * 2 + 0] = o0;
    out[g * 2 + 1] = o1;
}

// ---------------------------------------------------------------- edge head
// AB bf16 [N,128]: cols 0..63 = x3@ew1[:64], cols 64..127 = x3@ew1[64:]
__global__ __launch_bounds__(256) void k_edgehead(const ushort* __restrict__ AB,
                                                  const int* __restrict__ srcv,
                                                  const int* __restrict__ dstv,
                                                  const float* __restrict__ eb1,
                                                  const float* __restrict__ ew2,
                                                  const float* __restrict__ eb2,
                                                  const float* __restrict__ ew3,
                                                  const float* __restrict__ eb3,
                                                  float* __restrict__ out, int E) {
    __shared__ float w2[64 * 32];
    __shared__ float w3[32 * 3];
    __shared__ float b1s[64];
    __shared__ float b2s[32];
    __shared__ float b3s[3];
    int tid = threadIdx.x;
    for (int i = tid; i < 64 * 32; i += 256) w2[i] = ew2[i];
    for (int i = tid; i < 32 * 3; i += 256) w3[i] = ew3[i];
    if (tid < 64) b1s[tid] = eb1[tid];
    if (tid < 32) b2s[tid] = eb2[tid];
    if (tid < 3) b3s[tid] = eb3[tid];
    __syncthreads();
    int e = blockIdx.x * blockDim.x + tid;
    if (e >= E) return;
    int s = srcv[e], d = dstv[e];
    const uint4* Ar = (const uint4*)(AB + (size_t)s * 128);
    const uint4* Br = (const uint4*)(AB + (size_t)d * 128 + 64);
    float h2[32];
    #pragma unroll
    for (int j = 0; j < 32; ++j) h2[j] = 0.f;
    #pragma unroll
    for (int q = 0; q < 8; ++q) {
        uint4 ua = Ar[q], ub = Br[q];
        float af[8], bfv[8];
        af[0] = bflo(ua.x); af[1] = bfhi(ua.x); af[2] = bflo(ua.y); af[3] = bfhi(ua.y);
        af[4] = bflo(ua.z); af[5] = bfhi(ua.z); af[6] = bflo(ua.w); af[7] = bfhi(ua.w);
        bfv[0] = bflo(ub.x); bfv[1] = bfhi(ub.x); bfv[2] = bflo(ub.y); bfv[3] = bfhi(ub.y);
        bfv[4] = bflo(ub.z); bfv[5] = bfhi(ub.z); bfv[6] = bflo(ub.w); bfv[7] = bfhi(ub.w);
        #pragma unroll
        for (int t = 0; t < 8; ++t) {
            int k = q * 8 + t;
            float h1 = fmaxf(af[t] + bfv[t] + b1s[k], 0.f);
            #pragma unroll
            for (int j = 0; j < 32; ++j) h2[j] += h1 * w2[k * 32 + j];
        }
    }
    float o0 = b3s[0], o1 = b3s[1], o2 = b3s[2];
    #pragma unroll
    for (int j = 0; j < 32; ++j) {
        float hh = fmaxf(h2[j] + b2s[j], 0.f);
        o0 += hh * w3[j * 3 + 0];
        o1 += hh * w3[j * 3 + 1];
        o2 += hh * w3[j * 3 + 2];
    }
    out[200000 + (size_t)e * 3 + 0] = o0;
    out[200000 + (size_t)e * 3 + 1] = o1;
    out[200000 + (size_t)e * 3 + 2] = o2;
}

// ---------------------------------------------------------------- launch
extern "C" void kernel_launch(void* const* d_in, const int* in_sizes, int n_in,
                              void* d_out, int out_size, void* d_ws, size_t ws_size,
                              hipStream_t stream) {
    const float* x     = (const float*)d_in[0];
    const int*   ei    = (const int*)d_in[1];
    const int*   et    = (const int*)d_in[2];
    const float* W1    = (const float*)d_in[3];
    const float* root1 = (const float*)d_in[4];
    const float* b1    = (const float*)d_in[5];
    const float* W2    = (const float*)d_in[6];
    const float* root2 = (const float*)d_in[7];
    const float* b2    = (const float*)d_in[8];
    const float* W3    = (const float*)d_in[9];
    const float* root3 = (const float*)d_in[10];
    const float* b3    = (const float*)d_in[11];
    const float* nw1   = (const float*)d_in[12];
    const float* nb1   = (const float*)d_in[13];
    const float* nw2   = (const float*)d_in[14];
    const float* nb2   = (const float*)d_in[15];
    const float* ew1   = (const float*)d_in[16];
    const float* eb1   = (const float*)d_in[17];
    const float* ew2   = (const float*)d_in[18];
    const float* eb2   = (const float*)d_in[19];
    const float* ew3   = (const float*)d_in[20];
    const float* eb3   = (const float*)d_in[21];
    float* out = (float*)d_out;

    const int N = MN, E = ME;
    const int* srcv = ei;
    const int* dstv = ei + E;

    char* w = (char*)d_ws;
    ushort* Yb   = (ushort*)w; w += (size_t)N * 256 * 2;
    ushort* X1b  = (ushort*)w; w += (size_t)N * 64 * 2;
    ushort* X2b  = (ushort*)w; w += (size_t)N * 64 * 2;
    ushort* X3b  = (ushort*)w; w += (size_t)N * 64 * 2;
    ushort* ABb  = (ushort*)w; w += (size_t)N * 128 * 2;
    ushort* BT1  = (ushort*)w; w += 256 * 800 * 2;
    ushort* BT2  = (ushort*)w; w += 256 * 64 * 2;
    ushort* BT3  = (ushort*)w; w += 256 * 64 * 2;
    ushort* BTab = (ushort*)w; w += 128 * 64 * 2;
    int* deg     = (int*)w; w += (size_t)N * 4;
    int* row_ptr = (int*)w; w += (size_t)(N + 1) * 4;
    int* cursor  = (int*)w; w += (size_t)N * 4;
    int* esrt    = (int*)w; w += (size_t)E * 4;
    int* csums   = (int*)w; w += 512 * 4;

    // ---- CSR build
    hipMemsetAsync(deg, 0, N * sizeof(int), stream);
    k_deg<<<(E + 255) / 256, 256, 0, stream>>>(dstv, deg, E);
    int nchunks = (N + 255) / 256;
    k_scan1<<<nchunks, 256, 0, stream>>>(deg, row_ptr, csums, N);
    k_scan2<<<1, 512, 0, stream>>>(csums, nchunks);
    k_scan3<<<(N + 256) / 256, 256, 0, stream>>>(row_ptr, csums, cursor, N, E);
    k_fill<<<(E + 255) / 256, 256, 0, stream>>>(srcv, dstv, et, cursor, esrt, E);

    // ---- weight packs (bf16 B^T)
    k_pack_bt<<<(256 * 800 + 255) / 256, 256, 0, stream>>>(root1, W1, BT1, KIN, 800);
    k_pack_bt<<<(256 * 64 + 255) / 256, 256, 0, stream>>>(root2, W2, BT2, 64, 64);
    k_pack_bt<<<(256 * 64 + 255) / 256, 256, 0, stream>>>(root3, W3, BT3, 64, 64);
    k_packwab_bt<<<(128 * 64 + 255) / 256, 256, 0, stream>>>(ew1, BTab);

    int gx = (N + 127) / 128;  // 782
    int agg_grid = (N * 64 + 255) / 256;

    // ---- layer 1 (A fp32 fused-convert)
    k_mm<true, 256><<<dim3(gx, 1), 512, 0, stream>>>(x, BT1, Yb, N, KIN, 800, 256);
    k_agg<<<agg_grid, 256, 0, stream>>>(Yb, row_ptr, esrt, b1, nullptr, X1b, 1, N);

    // ---- layer 2
    k_mm<false, 256><<<dim3(gx, 1), 512, 0, stream>>>(X1b, BT2, Yb, N, 64, 64, 256);
    k_agg<<<agg_grid, 256, 0, stream>>>(Yb, row_ptr, esrt, b2, nullptr, X2b, 1, N);

    // ---- layer 3 (+ residual X1, no relu)
    k_mm<false, 256><<<dim3(gx, 1), 512, 0, stream>>>(X2b, BT3, Yb, N, 64, 64, 256);
    k_agg<<<agg_grid, 256, 0, stream>>>(Yb, row_ptr, esrt, b3, X1b, X3b, 0, N);

    // ---- node head
    k_nodehead<<<(N + 255) / 256, 256, 0, stream>>>(X3b, nw1, nb1, nw2, nb2, out, N);

    // ---- edge head
    k_mm<false, 128><<<dim3(gx, 1), 512, 0, stream>>>(X3b, BTab, ABb, N, 64, 64, 128);
    k_edgehead<<<(E + 255) / 256, 256, 0, stream>>>(ABb, srcv, dstv, eb1, ew2, eb2, ew3, eb3, out, E);
}

// Round 5
// 1244.485 us; speedup vs baseline: 1.9701x; 1.3031x over previous
//
#include <hip/hip_runtime.h>

typedef unsigned int uint;
typedef unsigned short ushort;
typedef short short8 __attribute__((ext_vector_type(8)));
typedef float f32x4 __attribute__((ext_vector_type(4)));
typedef float float4u __attribute__((ext_vector_type(4), aligned(4)));

#define MN 100000
#define ME 1600000
#define KIN 770

__device__ __forceinline__ ushort f2bf(float f) {
    union { float f; uint u; } c; c.f = f;
    uint r = (c.u + 0x7fffu + ((c.u >> 16) & 1u)) >> 16;
    return (ushort)r;
}
__device__ __forceinline__ float bf2f(ushort h) {
    union { uint u; float f; } c; c.u = ((uint)h) << 16;
    return c.f;
}
__device__ __forceinline__ float bflo(uint w) {
    union { uint u; float f; } c; c.u = w << 16; return c.f;
}
__device__ __forceinline__ float bfhi(uint w) {
    union { uint u; float f; } c; c.u = w & 0xffff0000u; return c.f;
}

// ---------------------------------------------------------------- CSR build
__global__ void k_deg(const int* __restrict__ dstv, int* __restrict__ deg, int E) {
    int e = blockIdx.x * blockDim.x + threadIdx.x;
    if (e < E) atomicAdd(&deg[dstv[e]], 1);
}

__global__ void k_scan1(const int* __restrict__ deg, int* __restrict__ excl,
                        int* __restrict__ csums, int n) {
    __shared__ int a[256], b[256];
    int tid = threadIdx.x;
    int g = blockIdx.x * 256 + tid;
    int v = (g < n) ? deg[g] : 0;
    int *cur = a, *nxt = b;
    cur[tid] = v;
    __syncthreads();
    for (int off = 1; off < 256; off <<= 1) {
        int t = cur[tid];
        if (tid >= off) t += cur[tid - off];
        nxt[tid] = t;
        __syncthreads();
        int* tmp = cur; cur = nxt; nxt = tmp;
    }
    int inc = cur[tid];
    if (g < n) excl[g] = inc - v;
    if (tid == 255) csums[blockIdx.x] = inc;
}

__global__ void k_scan2(int* __restrict__ csums, int nchunks) {
    __shared__ int a[512], b[512];
    int tid = threadIdx.x;
    int v = (tid < nchunks) ? csums[tid] : 0;
    int *cur = a, *nxt = b;
    cur[tid] = v;
    __syncthreads();
    for (int off = 1; off < 512; off <<= 1) {
        int t = cur[tid];
        if (tid >= off) t += cur[tid - off];
        nxt[tid] = t;
        __syncthreads();
        int* tmp = cur; cur = nxt; nxt = tmp;
    }
    int inc = cur[tid];
    if (tid < nchunks) csums[tid] = inc - v;
}

__global__ void k_scan3(int* __restrict__ row_ptr, const int* __restrict__ csums,
                        int* __restrict__ cursor, int n, int E) {
    int g = blockIdx.x * blockDim.x + threadIdx.x;
    if (g < n) {
        int v = row_ptr[g] + csums[g >> 8];
        row_ptr[g] = v;
        cursor[g] = v;
    }
    if (g == n) row_ptr[n] = E;
}

// scatter edges into CSR slots; esrt = src | rel<<17; dstp = dst; eid = original edge id
__global__ void k_fill(const int* __restrict__ srcv, const int* __restrict__ dstv,
                       const int* __restrict__ et, int* __restrict__ cursor,
                       int* __restrict__ esrt, int* __restrict__ dstp,
                       int* __restrict__ eid, int E) {
    int e = blockIdx.x * blockDim.x + threadIdx.x;
    if (e < E) {
        int d = dstv[e];
        int pos = atomicAdd(&cursor[d], 1);
        esrt[pos] = srcv[e] | (et[e] << 17);
        dstp[pos] = d;
        eid[pos] = e;
    }
}

// ---------------------------------------------------------------- weight packing (B^T bf16)
__global__ void k_pack_bt(const float* __restrict__ root, const float* __restrict__ W,
                          ushort* __restrict__ out, int K, int Kp) {
    int idx = blockIdx.x * blockDim.x + threadIdx.x;
    if (idx >= 256 * Kp) return;
    int j = idx / Kp, k = idx - j * Kp;
    float v = 0.f;
    if (k < K) {
        if (j < 64) v = root[k * 64 + j];
        else {
            int r = (j >> 6) - 1, jj = j & 63;
            v = W[((size_t)r * K + k) * 64 + jj];
        }
    }
    out[idx] = f2bf(v);
}

__global__ void k_packwab_bt(const float* __restrict__ ew1, ushort* __restrict__ out) {
    int idx = blockIdx.x * blockDim.x + threadIdx.x;
    if (idx >= 128 * 64) return;
    int j = idx >> 6, k = idx & 63;
    float v = (j < 64) ? ew1[k * 64 + j] : ew1[(64 + k) * 64 + (j - 64)];
    out[idx] = f2bf(v);
}

// ---------------------------------------------------------------- bf16 MFMA GEMM
template<bool AFP32, int BN>
__global__ __launch_bounds__(512) void k_mm(const void* __restrict__ Ain,
                                            const ushort* __restrict__ BT,
                                            ushort* __restrict__ C,
                                            int M, int K, int Kp, int Nc) {
    constexpr int WN = BN / 4;
    constexpr int NF = WN / 16;
    constexpr int NBS = (4 * BN) / 512;
    __shared__ uint4 lds4[512 + 4 * BN];
    int tid = threadIdx.x;
    int lane = tid & 63, wid = tid >> 6;
    int l15 = lane & 15, kq = lane >> 4;
    int wm = wid >> 2, wn = wid & 3;
    int m0 = blockIdx.x * 128;
    int n0 = blockIdx.y * BN;

    int s_kp = tid >> 7;
    int s_row = tid & 127;
    int gm = m0 + s_row; if (gm > M - 1) gm = M - 1;

    const float*  Af = (const float*)Ain;
    const ushort* Ab = (const ushort*)Ain;

    f32x4 acc[4][NF];
    #pragma unroll
    for (int m = 0; m < 4; ++m)
        #pragma unroll
        for (int n = 0; n < NF; ++n)
            acc[m][n] = (f32x4)0.f;

    int nkt = (K + 31) >> 5;
    uint4 stA, stB[NBS];

    auto loadA = [&](int kt) {
        int k0 = kt << 5;
        int kb = k0 + s_kp * 8;
        if constexpr (AFP32) {
            const float* ap = Af + (size_t)gm * K + kb;
            float v[8];
            if (k0 + 32 <= K) {
                *(float4u*)&v[0] = *(const float4u*)ap;
                *(float4u*)&v[4] = *(const float4u*)(ap + 4);
            } else {
                #pragma unroll
                for (int i = 0; i < 8; ++i)
                    v[i] = (kb + i < K) ? ap[i] : 0.f;
            }
            uint w[4];
            #pragma unroll
            for (int i = 0; i < 4; ++i)
                w[i] = (uint)f2bf(v[2 * i]) | ((uint)f2bf(v[2 * i + 1]) << 16);
            stA = make_uint4(w[0], w[1], w[2], w[3]);
        } else {
            stA = *(const uint4*)(Ab + (size_t)gm * K + kb);
        }
    };
    auto loadB = [&](int kt) {
        int k0 = kt << 5;
        #pragma unroll
        for (int is = 0; is < NBS; ++is) {
            int slot = is * 512 + tid;
            int kp = slot / BN;
            int col = slot & (BN - 1);
            stB[is] = *(const uint4*)(BT + (size_t)(n0 + col) * Kp + k0 + kp * 8);
        }
    };

    loadA(0); loadB(0);
    for (int kt = 0; kt < nkt; ++kt) {
        __syncthreads();
        lds4[tid] = stA;
        #pragma unroll
        for (int is = 0; is < NBS; ++is)
            lds4[512 + is * 512 + tid] = stB[is];
        __syncthreads();
        if (kt + 1 < nkt) { loadA(kt + 1); loadB(kt + 1); }
        const short8* Asv = (const short8*)lds4;
        const short8* Bsv = (const short8*)(lds4 + 512);
        short8 a[4], b[NF];
        #pragma unroll
        for (int m = 0; m < 4; ++m)
            a[m] = Asv[kq * 128 + wm * 64 + m * 16 + l15];
        #pragma unroll
        for (int n = 0; n < NF; ++n)
            b[n] = Bsv[kq * BN + wn * WN + n * 16 + l15];
        #pragma unroll
        for (int m = 0; m < 4; ++m)
            #pragma unroll
            for (int n = 0; n < NF; ++n)
                acc[m][n] = __builtin_amdgcn_mfma_f32_16x16x32_bf16(a[m], b[n], acc[m][n], 0, 0, 0);
    }

    #pragma unroll
    for (int m = 0; m < 4; ++m) {
        int rbase = m0 + wm * 64 + m * 16 + kq * 4;
        #pragma unroll
        for (int n = 0; n < NF; ++n) {
            int col = n0 + wn * WN + n * 16 + l15;
            #pragma unroll
            for (int rg = 0; rg < 4; ++rg) {
                int r = rbase + rg;
                if (r < M) C[(size_t)r * Nc + col] = f2bf(acc[m][n][rg]);
            }
        }
    }
}

// ---------------------------------------------------------------- RGCN aggregation (bf16)
// One wave per node; lane = feature. 4-way unrolled edge loop for MLP (4 outstanding gathers).
__global__ __launch_bounds__(256) void k_agg(const ushort* __restrict__ Y,
                                             const int* __restrict__ row_ptr,
                                             const int* __restrict__ esrt,
                                             const float* __restrict__ bias,
                                             const ushort* __restrict__ resid,
                                             ushort* __restrict__ Xout,
                                             int do_relu, int n) {
    int wid = (blockIdx.x * blockDim.x + threadIdx.x) >> 6;
    int lane = threadIdx.x & 63;
    if (wid >= n) return;
    int beg = row_ptr[wid], end = row_ptr[wid + 1];
    // issue self-term load early (independent of the gather loop)
    float self = bf2f(Y[(size_t)wid * 256 + lane]);
    float bv = bias[lane];
    float a0 = 0.f, a1 = 0.f, a2 = 0.f;
    int c0 = 0, c1 = 0, c2 = 0;
    int e = beg;
    for (; e + 4 <= end; e += 4) {
        int p0 = esrt[e], p1 = esrt[e + 1], p2 = esrt[e + 2], p3 = esrt[e + 3];
        float v0 = bf2f(Y[(size_t)(p0 & 0x1FFFF) * 256 + 64 + ((p0 >> 17) << 6) + lane]);
        float v1 = bf2f(Y[(size_t)(p1 & 0x1FFFF) * 256 + 64 + ((p1 >> 17) << 6) + lane]);
        float v2 = bf2f(Y[(size_t)(p2 & 0x1FFFF) * 256 + 64 + ((p2 >> 17) << 6) + lane]);
        float v3 = bf2f(Y[(size_t)(p3 & 0x1FFFF) * 256 + 64 + ((p3 >> 17) << 6) + lane]);
        int r0 = p0 >> 17, r1 = p1 >> 17, r2 = p2 >> 17, r3 = p3 >> 17;
        if (r0 == 0) { a0 += v0; c0++; } else if (r0 == 1) { a1 += v0; c1++; } else { a2 += v0; c2++; }
        if (r1 == 0) { a0 += v1; c0++; } else if (r1 == 1) { a1 += v1; c1++; } else { a2 += v1; c2++; }
        if (r2 == 0) { a0 += v2; c0++; } else if (r2 == 1) { a1 += v2; c1++; } else { a2 += v2; c2++; }
        if (r3 == 0) { a0 += v3; c0++; } else if (r3 == 1) { a1 += v3; c1++; } else { a2 += v3; c2++; }
    }
    for (; e < end; ++e) {
        int p = esrt[e];
        int r = p >> 17;
        float v = bf2f(Y[(size_t)(p & 0x1FFFF) * 256 + 64 + (r << 6) + lane]);
        if (r == 0) { a0 += v; c0++; } else if (r == 1) { a1 += v; c1++; } else { a2 += v; c2++; }
    }
    float res = self + bv;
    if (c0) res += a0 / (float)c0;
    if (c1) res += a1 / (float)c1;
    if (c2) res += a2 / (float)c2;
    if (do_relu) res = fmaxf(res, 0.f);
    if (resid) res += bf2f(resid[(size_t)wid * 64 + lane]);
    Xout[(size_t)wid * 64 + lane] = f2bf(res);
}

// ---------------------------------------------------------------- node head
__global__ __launch_bounds__(256) void k_nodehead(const ushort* __restrict__ X3,
                                                  const float* __restrict__ nw1,
                                                  const float* __restrict__ nb1,
                                                  const float* __restrict__ nw2,
                                                  const float* __restrict__ nb2,
                                                  float* __restrict__ out, int n) {
    __shared__ float w1[64 * 32];
    __shared__ float w2[32 * 2];
    __shared__ float b1s[32];
    __shared__ float b2s[2];
    int tid = threadIdx.x;
    for (int i = tid; i < 64 * 32; i += 256) w1[i] = nw1[i];
    for (int i = tid; i < 32 * 2; i += 256) w2[i] = nw2[i];
    if (tid < 32) b1s[tid] = nb1[tid];
    if (tid < 2) b2s[tid] = nb2[tid];
    __syncthreads();
    int g = blockIdx.x * blockDim.x + tid;
    if (g >= n) return;
    float x[64];
    const uint4* xr = (const uint4*)(X3 + (size_t)g * 64);
    #pragma unroll
    for (int q = 0; q < 8; ++q) {
        uint4 u = xr[q];
        x[q * 8 + 0] = bflo(u.x); x[q * 8 + 1] = bfhi(u.x);
        x[q * 8 + 2] = bflo(u.y); x[q * 8 + 3] = bfhi(u.y);
        x[q * 8 + 4] = bflo(u.z); x[q * 8 + 5] = bfhi(u.z);
        x[q * 8 + 6] = bflo(u.w); x[q * 8 + 7] = bfhi(u.w);
    }
    float o0 = b2s[0], o1 = b2s[1];
    for (int j = 0; j < 32; ++j) {
        float h = b1s[j];
        #pragma unroll
        for (int k = 0; k < 64; ++k) h += x[k] * w1[k * 32 + j];
        h = fmaxf(h, 0.f);
        o0 += h * w2[j * 2 + 0];
        o1 += h * w2[j * 2 + 1];
    }
    out[g * 2 + 0] = o0;
    out[g * 2 + 1] = o1;
}

// ---------------------------------------------------------------- edge head (dst-sorted)
// Processes edges in CSR (dst-sorted) order: B-gather streams (shared dst), A-gather random.
// Writes scatter via eid to preserve original edge order.
__global__ __launch_bounds__(256) void k_edgehead(const ushort* __restrict__ AB,
                                                  const int* __restrict__ esrt,
                                                  const int* __restrict__ dstp,
                                                  const int* __restrict__ eid,
                                                  const float* __restrict__ eb1,
                                                  const float* __restrict__ ew2,
                                                  const float* __restrict__ eb2,
                                                  const float* __restrict__ ew3,
                                                  const float* __restrict__ eb3,
                                                  float* __restrict__ out, int E) {
    __shared__ float w2[64 * 32];
    __shared__ float w3[32 * 3];
    __shared__ float b1s[64];
    __shared__ float b2s[32];
    __shared__ float b3s[3];
    int tid = threadIdx.x;
    for (int i = tid; i < 64 * 32; i += 256) w2[i] = ew2[i];
    for (int i = tid; i < 32 * 3; i += 256) w3[i] = ew3[i];
    if (tid < 64) b1s[tid] = eb1[tid];
    if (tid < 32) b2s[tid] = eb2[tid];
    if (tid < 3) b3s[tid] = eb3[tid];
    __syncthreads();
    int p = blockIdx.x * blockDim.x + tid;
    if (p >= E) return;
    int s = esrt[p] & 0x1FFFF;
    int d = dstp[p];
    int e = eid[p];
    // prefetch the random (src) side fully into registers first: 8 outstanding loads
    const uint4* Ar = (const uint4*)(AB + (size_t)s * 128);
    uint4 a4[8];
    #pragma unroll
    for (int q = 0; q < 8; ++q) a4[q] = Ar[q];
    const uint4* Br = (const uint4*)(AB + (size_t)d * 128 + 64);
    float h2[32];
    #pragma unroll
    for (int j = 0; j < 32; ++j) h2[j] = 0.f;
    #pragma unroll
    for (int q = 0; q < 8; ++q) {
        uint4 ua = a4[q], ub = Br[q];
        float af[8], bfv[8];
        af[0] = bflo(ua.x); af[1] = bfhi(ua.x); af[2] = bflo(ua.y); af[3] = bfhi(ua.y);
        af[4] = bflo(ua.z); af[5] = bfhi(ua.z); af[6] = bflo(ua.w); af[7] = bfhi(ua.w);
        bfv[0] = bflo(ub.x); bfv[1] = bfhi(ub.x); bfv[2] = bflo(ub.y); bfv[3] = bfhi(ub.y);
        bfv[4] = bflo(ub.z); bfv[5] = bfhi(ub.z); bfv[6] = bflo(ub.w); bfv[7] = bfhi(ub.w);
        #pragma unroll
        for (int t = 0; t < 8; ++t) {
            int k = q * 8 + t;
            float h1 = fmaxf(af[t] + bfv[t] + b1s[k], 0.f);
            #pragma unroll
            for (int j = 0; j < 32; ++j) h2[j] += h1 * w2[k * 32 + j];
        }
    }
    float o0 = b3s[0], o1 = b3s[1], o2 = b3s[2];
    #pragma unroll
    for (int j = 0; j < 32; ++j) {
        float hh = fmaxf(h2[j] + b2s[j], 0.f);
        o0 += hh * w3[j * 3 + 0];
        o1 += hh * w3[j * 3 + 1];
        o2 += hh * w3[j * 3 + 2];
    }
    out[200000 + (size_t)e * 3 + 0] = o0;
    out[200000 + (size_t)e * 3 + 1] = o1;
    out[200000 + (size_t)e * 3 + 2] = o2;
}

// ---------------------------------------------------------------- launch
extern "C" void kernel_launch(void* const* d_in, const int* in_sizes, int n_in,
                              void* d_out, int out_size, void* d_ws, size_t ws_size,
                              hipStream_t stream) {
    const float* x     = (const float*)d_in[0];
    const int*   ei    = (const int*)d_in[1];
    const int*   et    = (const int*)d_in[2];
    const float* W1    = (const float*)d_in[3];
    const float* root1 = (const float*)d_in[4];
    const float* b1    = (const float*)d_in[5];
    const float* W2    = (const float*)d_in[6];
    const float* root2 = (const float*)d_in[7];
    const float* b2    = (const float*)d_in[8];
    const float* W3    = (const float*)d_in[9];
    const float* root3 = (const float*)d_in[10];
    const float* b3    = (const float*)d_in[11];
    const float* nw1   = (const float*)d_in[12];
    const float* nb1   = (const float*)d_in[13];
    const float* nw2   = (const float*)d_in[14];
    const float* nb2   = (const float*)d_in[15];
    const float* ew1   = (const float*)d_in[16];
    const float* eb1   = (const float*)d_in[17];
    const float* ew2   = (const float*)d_in[18];
    const float* eb2   = (const float*)d_in[19];
    const float* ew3   = (const float*)d_in[20];
    const float* eb3   = (const float*)d_in[21];
    float* out = (float*)d_out;

    const int N = MN, E = ME;
    const int* srcv = ei;
    const int* dstv = ei + E;

    char* w = (char*)d_ws;
    ushort* Yb   = (ushort*)w; w += (size_t)N * 256 * 2;
    ushort* X1b  = (ushort*)w; w += (size_t)N * 64 * 2;
    ushort* X2b  = (ushort*)w; w += (size_t)N * 64 * 2;
    ushort* X3b  = (ushort*)w; w += (size_t)N * 64 * 2;
    ushort* ABb  = (ushort*)w; w += (size_t)N * 128 * 2;
    ushort* BT1  = (ushort*)w; w += 256 * 800 * 2;
    ushort* BT2  = (ushort*)w; w += 256 * 64 * 2;
    ushort* BT3  = (ushort*)w; w += 256 * 64 * 2;
    ushort* BTab = (ushort*)w; w += 128 * 64 * 2;
    int* deg     = (int*)w; w += (size_t)N * 4;
    int* row_ptr = (int*)w; w += (size_t)(N + 1) * 4;
    int* cursor  = (int*)w; w += (size_t)N * 4;
    int* esrt    = (int*)w; w += (size_t)E * 4;
    int* dstp    = (int*)w; w += (size_t)E * 4;
    int* eid     = (int*)w; w += (size_t)E * 4;
    int* csums   = (int*)w; w += 512 * 4;

    // ---- CSR build
    hipMemsetAsync(deg, 0, N * sizeof(int), stream);
    k_deg<<<(E + 255) / 256, 256, 0, stream>>>(dstv, deg, E);
    int nchunks = (N + 255) / 256;
    k_scan1<<<nchunks, 256, 0, stream>>>(deg, row_ptr, csums, N);
    k_scan2<<<1, 512, 0, stream>>>(csums, nchunks);
    k_scan3<<<(N + 256) / 256, 256, 0, stream>>>(row_ptr, csums, cursor, N, E);
    k_fill<<<(E + 255) / 256, 256, 0, stream>>>(srcv, dstv, et, cursor, esrt, dstp, eid, E);

    // ---- weight packs (bf16 B^T)
    k_pack_bt<<<(256 * 800 + 255) / 256, 256, 0, stream>>>(root1, W1, BT1, KIN, 800);
    k_pack_bt<<<(256 * 64 + 255) / 256, 256, 0, stream>>>(root2, W2, BT2, 64, 64);
    k_pack_bt<<<(256 * 64 + 255) / 256, 256, 0, stream>>>(root3, W3, BT3, 64, 64);
    k_packwab_bt<<<(128 * 64 + 255) / 256, 256, 0, stream>>>(ew1, BTab);

    int gx = (N + 127) / 128;  // 782
    int agg_grid = (N * 64 + 255) / 256;

    // ---- layer 1 (A fp32 fused-convert)
    k_mm<true, 256><<<dim3(gx, 1), 512, 0, stream>>>(x, BT1, Yb, N, KIN, 800, 256);
    k_agg<<<agg_grid, 256, 0, stream>>>(Yb, row_ptr, esrt, b1, nullptr, X1b, 1, N);

    // ---- layer 2
    k_mm<false, 256><<<dim3(gx, 1), 512, 0, stream>>>(X1b, BT2, Yb, N, 64, 64, 256);
    k_agg<<<agg_grid, 256, 0, stream>>>(Yb, row_ptr, esrt, b2, nullptr, X2b, 1, N);

    // ---- layer 3 (+ residual X1, no relu)
    k_mm<false, 256><<<dim3(gx, 1), 512, 0, stream>>>(X2b, BT3, Yb, N, 64, 64, 256);
    k_agg<<<agg_grid, 256, 0, stream>>>(Yb, row_ptr, esrt, b3, X1b, X3b, 0, N);

    // ---- node head
    k_nodehead<<<(N + 255) / 256, 256, 0, stream>>>(X3b, nw1, nb1, nw2, nb2, out, N);

    // ---- edge head (dst-sorted order)
    k_mm<false, 128><<<dim3(gx, 1), 512, 0, stream>>>(X3b, BTab, ABb, N, 64, 64, 128);
    k_edgehead<<<(E + 255) / 256, 256, 0, stream>>>(ABb, esrt, dstp, eid, eb1, ew2, eb2, ew3, eb3, out, E);
}